// Round 2
// baseline (1332.894 us; speedup 1.0000x reference)
//
#include <hip/hip_runtime.h>

constexpr int N = 200000;
constexpr int E = 5000000;
constexpr int F = 16;

// ---- degree: one atomic per edge ----
__global__ void deg_kernel(const int* __restrict__ dst, float* __restrict__ deg) {
    int stride = gridDim.x * blockDim.x;
    for (int e = blockIdx.x * blockDim.x + threadIdx.x; e < E; e += stride)
        atomicAdd(&deg[dst[e]], 1.0f);
}

__global__ void inv_deg_kernel(float* __restrict__ deg) {
    int i = blockIdx.x * blockDim.x + threadIdx.x;
    if (i < N) deg[i] = 1.0f / fmaxf(deg[i], 1.0f);
}

// ---- scatter-add of features: 16 lanes per edge, lane k handles feature k ----
__global__ void scatter_kernel(const float* __restrict__ h,
                               const int* __restrict__ src,
                               const int* __restrict__ dst,
                               float* __restrict__ agg) {
    const long long total = (long long)E * F;
    const long long stride = (long long)gridDim.x * blockDim.x;
    for (long long gid = (long long)blockIdx.x * blockDim.x + threadIdx.x; gid < total; gid += stride) {
        const int e = (int)(gid >> 4);
        const int k = (int)(gid & (F - 1));
        const int s = src[e];
        const int d = dst[e];
        atomicAdd(&agg[d * F + k], h[s * F + k]);
    }
}

// ---- per-node SAGE update: out = relu(mean@Wl.T + bl + x@Wr.T), optional fused fc+relu ----
__global__ void update_kernel(const float* __restrict__ agg,
                              const float* __restrict__ inv_deg,
                              const float* __restrict__ hin,
                              float* __restrict__ hout,
                              const float* __restrict__ Wl,
                              const float* __restrict__ bl,
                              const float* __restrict__ Wr,
                              const float* __restrict__ fcW,
                              const float* __restrict__ fcb,
                              int do_fc) {
    int i = blockIdx.x * blockDim.x + threadIdx.x;
    if (i >= N) return;
    float m[F], xi[F], o[F];
    const float inv = inv_deg[i];
#pragma unroll
    for (int k = 0; k < F; k += 4) {
        float4 a = *reinterpret_cast<const float4*>(&agg[i * F + k]);
        float4 b = *reinterpret_cast<const float4*>(&hin[i * F + k]);
        m[k] = a.x * inv; m[k + 1] = a.y * inv; m[k + 2] = a.z * inv; m[k + 3] = a.w * inv;
        xi[k] = b.x; xi[k + 1] = b.y; xi[k + 2] = b.z; xi[k + 3] = b.w;
    }
#pragma unroll
    for (int oi = 0; oi < F; oi++) {
        float acc = bl[oi];
#pragma unroll
        for (int k = 0; k < F; k++)
            acc = fmaf(m[k], Wl[oi * F + k], fmaf(xi[k], Wr[oi * F + k], acc));
        o[oi] = fmaxf(acc, 0.0f);   // relu follows every SAGE layer in this graph
    }
    if (do_fc) {
#pragma unroll
        for (int oi = 0; oi < F; oi++) {
            float acc = fcb[oi];
#pragma unroll
            for (int k = 0; k < F; k++) acc = fmaf(o[k], fcW[oi * F + k], acc);
            xi[oi] = fmaxf(acc, 0.0f);
        }
#pragma unroll
        for (int k = 0; k < F; k += 4)
            *reinterpret_cast<float4*>(&hout[i * F + k]) =
                make_float4(xi[k], xi[k + 1], xi[k + 2], xi[k + 3]);
    } else {
#pragma unroll
        for (int k = 0; k < F; k += 4)
            *reinterpret_cast<float4*>(&hout[i * F + k]) =
                make_float4(o[k], o[k + 1], o[k + 2], o[k + 3]);
    }
}

// ---- final layer: SAGE(only 8 outputs) + relu + fc2(8x8) + relu + softmax ----
__global__ void final_kernel(const float* __restrict__ agg,
                             const float* __restrict__ inv_deg,
                             const float* __restrict__ hin,
                             const float* __restrict__ Wl,
                             const float* __restrict__ bl,
                             const float* __restrict__ Wr,
                             const float* __restrict__ fc2W,
                             const float* __restrict__ fc2b,
                             float* __restrict__ out) {
    int i = blockIdx.x * blockDim.x + threadIdx.x;
    if (i >= N) return;
    float m[F], xi[F];
    const float inv = inv_deg[i];
#pragma unroll
    for (int k = 0; k < F; k += 4) {
        float4 a = *reinterpret_cast<const float4*>(&agg[i * F + k]);
        float4 b = *reinterpret_cast<const float4*>(&hin[i * F + k]);
        m[k] = a.x * inv; m[k + 1] = a.y * inv; m[k + 2] = a.z * inv; m[k + 3] = a.w * inv;
        xi[k] = b.x; xi[k + 1] = b.y; xi[k + 2] = b.z; xi[k + 3] = b.w;
    }
    float t[8];
#pragma unroll
    for (int oi = 0; oi < 8; oi++) {   // slice [:, :8] -> only first 8 rows of Wl/Wr needed
        float acc = bl[oi];
#pragma unroll
        for (int k = 0; k < F; k++)
            acc = fmaf(m[k], Wl[oi * F + k], fmaf(xi[k], Wr[oi * F + k], acc));
        t[oi] = fmaxf(acc, 0.0f);
    }
    float u[8];
#pragma unroll
    for (int oi = 0; oi < 8; oi++) {
        float acc = fc2b[oi];
#pragma unroll
        for (int k = 0; k < 8; k++) acc = fmaf(t[k], fc2W[oi * 8 + k], acc);
        u[oi] = fmaxf(acc, 0.0f);
    }
    float mx = u[0];
#pragma unroll
    for (int oi = 1; oi < 8; oi++) mx = fmaxf(mx, u[oi]);
    float s = 0.0f;
#pragma unroll
    for (int oi = 0; oi < 8; oi++) { u[oi] = __expf(u[oi] - mx); s += u[oi]; }
    const float is = 1.0f / s;
#pragma unroll
    for (int k = 0; k < 8; k += 4)
        *reinterpret_cast<float4*>(&out[i * 8 + k]) =
            make_float4(u[k] * is, u[k + 1] * is, u[k + 2] * is, u[k + 3] * is);
}

extern "C" void kernel_launch(void* const* d_in, const int* in_sizes, int n_in,
                              void* d_out, int out_size, void* d_ws, size_t ws_size,
                              hipStream_t stream) {
    const float* x = (const float*)d_in[0];
    const int* edge = (const int*)d_in[1];   // harness passes integer inputs as int32
    const int* src = edge;
    const int* dst = edge + E;
    const float* c1_Wl = (const float*)d_in[2];
    const float* c1_bl = (const float*)d_in[3];
    const float* c1_Wr = (const float*)d_in[4];
    const float* c2_Wl = (const float*)d_in[5];
    const float* c2_bl = (const float*)d_in[6];
    const float* c2_Wr = (const float*)d_in[7];
    const float* fc1_W = (const float*)d_in[8];
    const float* fc1_b = (const float*)d_in[9];
    const float* fc2_W = (const float*)d_in[10];
    const float* fc2_b = (const float*)d_in[11];
    float* out = (float*)d_out;

    float* inv_deg = (float*)d_ws;        // N
    float* agg = inv_deg + N;             // N*F
    float* h = agg + (size_t)N * F;       // N*F

    const int TB = 256;
    const int nblk_nodes = (N + TB - 1) / TB;

    // degree (graph-only, once)
    hipMemsetAsync(inv_deg, 0, N * sizeof(float), stream);
    deg_kernel<<<2048, TB, 0, stream>>>(dst, inv_deg);
    inv_deg_kernel<<<nblk_nodes, TB, 0, stream>>>(inv_deg);

    // layer 0: x -> h (relu)
    hipMemsetAsync(agg, 0, (size_t)N * F * sizeof(float), stream);
    scatter_kernel<<<2048, TB, 0, stream>>>(x, src, dst, agg);
    update_kernel<<<nblk_nodes, TB, 0, stream>>>(agg, inv_deg, x, h,
        c1_Wl, c1_bl, c1_Wr, nullptr, nullptr, 0);

    // layer 1: h -> h (relu, fused fc1+relu)
    hipMemsetAsync(agg, 0, (size_t)N * F * sizeof(float), stream);
    scatter_kernel<<<2048, TB, 0, stream>>>(h, src, dst, agg);
    update_kernel<<<nblk_nodes, TB, 0, stream>>>(agg, inv_deg, h, h,
        c1_Wl + F * F, c1_bl + F, c1_Wr + F * F, fc1_W, fc1_b, 1);

    // layer 2: h -> h (relu)
    hipMemsetAsync(agg, 0, (size_t)N * F * sizeof(float), stream);
    scatter_kernel<<<2048, TB, 0, stream>>>(h, src, dst, agg);
    update_kernel<<<nblk_nodes, TB, 0, stream>>>(agg, inv_deg, h, h,
        c2_Wl, c2_bl, c2_Wr, nullptr, nullptr, 0);

    // layer 3: h -> out (relu, slice8, fc2+relu, softmax)
    hipMemsetAsync(agg, 0, (size_t)N * F * sizeof(float), stream);
    scatter_kernel<<<2048, TB, 0, stream>>>(h, src, dst, agg);
    final_kernel<<<nblk_nodes, TB, 0, stream>>>(agg, inv_deg, h,
        c2_Wl + F * F, c2_bl + F, c2_Wr + F * F, fc2_W, fc2_b, out);
}